// Round 16
// baseline (243.295 us; speedup 1.0000x reference)
//
#include <hip/hip_runtime.h>

// Problem constants (fixed by reference)
#define B_    2
#define NH_   4
#define T_    8
#define H_    14
#define W_    14
#define HW_   196             // H*W
#define HD_   96
#define DIM_  384
#define N_    1568            // T*H*W
#define BH_   (B_*NH_)        // 8
#define BN_   (B_*N_)         // 3136
#define BHN_  (BH_*N_)        // 12544
#define CAUG_ 160             // 96 + 36 one-hot/bias + 28 pad

typedef unsigned short bf_t;
typedef unsigned int   u32;
typedef __attribute__((ext_vector_type(8))) short bf16x8;
typedef __attribute__((ext_vector_type(4))) float f32x4;

#define LOG2E 1.4426950408889634f
#define QSCALE_LOG2E 0.14724445f   /* 96^-0.5 * log2(e) */

static __device__ __forceinline__ float lo16(u32 v){ union{u32 i; float f;}x; x.i = v<<16;           return x.f; }
static __device__ __forceinline__ float hi16(u32 v){ union{u32 i; float f;}x; x.i = v & 0xffff0000u; return x.f; }
static __device__ __forceinline__ float b2f(bf_t v){ union{u32 i; float f;}x; x.i = ((u32)v)<<16;    return x.f; }
static __device__ __forceinline__ bf_t  f2b(float f){
  union{float f; u32 i;} x; x.f = f;
  return (bf_t)((x.i + 0x7fffu + ((x.i>>16)&1u)) >> 16);   // RNE
}
static __device__ __forceinline__ u32 pack2(float a, float b){
  return (u32)f2b(a) | ((u32)f2b(b) << 16);
}
// fragment-tile index for a row-major [R][384] matrix element (row, k)
static __device__ __forceinline__ size_t ftidx(int row, int k){
  return ((((size_t)(row>>4))*12 + (k>>5))*64 + ((k>>3)&3)*16 + (row&15))*8 + (k&7);
}

// ---------------------------------------------------------------------------
// K0: cast x / qkv_w / proj_w fp32 -> bf16 in FRAGMENT-TILED layout, plus
// conv-weight transpose [96][27]->[27][96] fp32 (last 31 blocks).
// ---------------------------------------------------------------------------
#define NA_ (BN_*DIM_)        // 1,204,224
#define NB_ (3*DIM_*DIM_)     //   442,368
#define NC_ (DIM_*DIM_)       //   147,456
#define CAST_BLOCKS ((NA_+NB_+NC_)/4/256)   // 1752 exactly

__global__ __launch_bounds__(256) void k_cast(
    const float* __restrict__ a, bf_t* __restrict__ ad,
    const float* __restrict__ b, bf_t* __restrict__ bd,
    const float* __restrict__ c, bf_t* __restrict__ cd,
    const float* __restrict__ wq, const float* __restrict__ wk,
    const float* __restrict__ wv, float* __restrict__ tq,
    float* __restrict__ tk, float* __restrict__ tv){
  if (blockIdx.x < CAST_BLOCKS){
    const int i = blockIdx.x*256 + threadIdx.x;     // float4 index
    const int i4 = i*4;
    float4 v; bf_t* dst; int row, k;
    if (i4 < NA_){
      v = ((const float4*)a)[i];
      dst = ad; row = i4/DIM_; k = i4%DIM_;
    } else if (i4 < NA_+NB_){
      const int f = i4 - NA_;
      v = ((const float4*)b)[i - NA_/4];
      dst = bd; row = f/DIM_; k = f%DIM_;
    } else {
      const int f = i4 - NA_ - NB_;
      v = ((const float4*)c)[i - (NA_+NB_)/4];
      dst = cd; row = f/DIM_; k = f%DIM_;
    }
    ushort4 o; o.x = f2b(v.x); o.y = f2b(v.y); o.z = f2b(v.z); o.w = f2b(v.w);
    *(ushort4*)(dst + ftidx(row, k)) = o;           // k%4==0 -> 8B aligned
  } else {
    const int idx = (blockIdx.x - CAST_BLOCKS)*256 + threadIdx.x;
    if (idx >= 3*HD_*27) return;
    const int t = idx / (HD_*27), rem = idx % (HD_*27);
    const int ch = rem / 27, j = rem % 27;
    const float* s = (t==0)? wq : (t==1)? wk : wv;
    float* d       = (t==0)? tq : (t==1)? tk : tv;
    d[j*HD_ + ch] = s[ch*27 + j];
  }
}

// ---------------------------------------------------------------------------
// K1: QKV GEMM via MFMA, fragment-tiled operands. Wave tile 16x64, 4 waves
// M-stacked (block 64x64); grid (49,18) = 882 blocks x 4 = 3528 waves.
// ---------------------------------------------------------------------------
__global__ __launch_bounds__(256) void k_qkv(const bf_t* __restrict__ Xt,
    const bf_t* __restrict__ Wt,
    bf_t* __restrict__ q, bf_t* __restrict__ k, bf_t* __restrict__ v){
  const int wid = threadIdx.x >> 6, lane = threadIdx.x & 63;
  const int nl = lane & 15, quad = lane >> 4;
  const int mt  = blockIdx.x*4 + wid;       // 16-row tile, 0..195
  const int nt0 = blockIdx.y*4;             // 4 col-tiles of 16
  f32x4 acc[4];
  #pragma unroll
  for (int j = 0; j < 4; ++j) acc[j] = (f32x4){0.f,0.f,0.f,0.f};
  const bf_t* A0 = Xt + ((size_t)mt*12*64 + lane)*8;
  const bf_t* B0 = Wt + ((size_t)nt0*12*64 + lane)*8;
  #pragma unroll 3
  for (int k0 = 0; k0 < 12; ++k0){
    const bf16x8 a0 = *(const bf16x8*)(A0 + k0*512);
    bf16x8 bf[4];
    #pragma unroll
    for (int j = 0; j < 4; ++j) bf[j] = *(const bf16x8*)(B0 + (size_t)(j*12 + k0)*512);
    #pragma unroll
    for (int j = 0; j < 4; ++j)
      acc[j] = __builtin_amdgcn_mfma_f32_16x16x32_bf16(a0, bf[j], acc[j], 0, 0, 0);
  }
  #pragma unroll
  for (int r = 0; r < 4; ++r){
    const int m  = mt*16 + quad*4 + r;
    const int bb = m / N_, nn = m % N_;
    #pragma unroll
    for (int j = 0; j < 4; ++j){
      const int col = (nt0 + j)*16 + nl;
      const int s = col / DIM_, rem = col - s*DIM_;
      const int head = rem / HD_, hc = rem % HD_;
      bf_t* dst = (s==0) ? q : (s==1) ? k : v;
      dst[((size_t)(bb*NH_ + head)*N_ + nn)*HD_ + hc] = f2b(acc[j][r]);
    }
  }
}

static __device__ __forceinline__ void ln_butterfly(
    float v0, float v1, float& mean, float& rstd){
  float s  = v0 + v1;
  float s2 = v0*v0 + v1*v1;
  #pragma unroll
  for (int off = 32; off > 0; off >>= 1){
    s  += __shfl_xor(s,  off);
    s2 += __shfl_xor(s2, off);
  }
  mean = s * (1.f/HD_);
  const float var = fmaxf(s2*(1.f/HD_) - mean*mean, 0.f);
  rstd = rsqrtf(var + 1e-6f);
}

// ---------------------------------------------------------------------------
// K2: LDS-slab pooled conv+LN, 16 tokens/block, 512 THREADS (8 waves x 2
// tokens — double the independent streams per block for latency hiding).
// XCD-aware decode; slab-as-scratch union.
// ---------------------------------------------------------------------------
__global__ __launch_bounds__(512) void k_pool_slab(
    const bf_t* __restrict__ qr_, const bf_t* __restrict__ kr_, const bf_t* __restrict__ vr_,
    const float* __restrict__ wtq, const float* __restrict__ wtk, const float* __restrict__ wtv,
    const float* __restrict__ gq, const float* __restrict__ bq,
    const float* __restrict__ gk, const float* __restrict__ bk,
    const float* __restrict__ gv, const float* __restrict__ bv,
    const float* __restrict__ rph, const float* __restrict__ rpw,
    const float* __restrict__ rpt,
    bf_t* __restrict__ qp, bf_t* __restrict__ Qaug,
    bf_t* __restrict__ Kt, bf_t* __restrict__ Vtt){
  __shared__ __align__(16) bf_t slab[162][HD_];   // 31,104 B (also scratch)
  const int wid = threadIdx.x >> 6, lane = threadIdx.x & 63;
  const int bh   = blockIdx.x & 7;
  const int slot = blockIdx.x >> 3;               // 0..293
  const int sec  = slot / 98;
  const int tok0 = (slot % 98)*16;
  const bf_t*  src = (sec==0)? qr_ : (sec==1)? kr_ : vr_;
  const float* wt  = (sec==0)? wtq : (sec==1)? wtk : wtv;
  const float* g   = (sec==0)? gq  : (sec==1)? gk  : gv;
  const float* be  = (sec==0)? bq  : (sec==1)? bk  : bv;
  const bf_t* base = src + (size_t)bh*N_*HD_;

  // stage halo slab: row = a*54+b*18+c -> linear offset (a-1)*196+(b-1)*14+(c-1)
  for (int li = threadIdx.x; li < 162*12; li += 512){
    const int rw = li / 12, ss = li % 12;
    const int aa = rw/54, bb2 = (rw%54)/18, cc = rw%18;
    int nn = tok0 + (aa-1)*HW_ + (bb2-1)*W_ + (cc-1);
    nn = min(max(nn, 0), N_-1);
    *(uint4*)&slab[rw][ss*8] = *(const uint4*)(base + (size_t)nn*HD_ + ss*8);
  }
  __syncthreads();

  const int c0 = (lane < 48) ? 2*lane : 0;
  float2 wgt[27];
  #pragma unroll
  for (int j = 0; j < 27; ++j) wgt[j] = *(const float2*)(wt + j*HD_ + c0);
  const float gg0 = g[c0], gg1 = g[c0+1], be0 = be[c0], be1 = be[c0+1];

  float y0r[2], y1r[2];
  #pragma unroll 1
  for (int tk = 0; tk < 2; ++tk){
    const int u = wid*2 + tk;
    const int n = tok0 + u;
    const int tt = n / HW_; const int rm = n % HW_;
    const int hh = rm / W_, ww = rm % W_;
    float2 wm[27];
    #pragma unroll
    for (int j = 0; j < 27; ++j){
      const int dt = j/9 - 1, dh = (j%9)/3 - 1, dw = j%3 - 1;
      const bool ok = ((unsigned)(tt+dt) < (unsigned)T_)
                   && ((unsigned)(hh+dh) < (unsigned)H_)
                   && ((unsigned)(ww+dw) < (unsigned)W_);
      wm[j].x = ok ? wgt[j].x : 0.f;
      wm[j].y = ok ? wgt[j].y : 0.f;
    }
    u32 data[27];
    #pragma unroll
    for (int j = 0; j < 27; ++j){
      const int rj = (j/9)*54 + ((j%9)/3)*18 + (j%3) + u;
      data[j] = *(const u32*)&slab[rj][c0];
    }
    float v0 = 0.f, v1 = 0.f;
    #pragma unroll
    for (int j = 0; j < 27; ++j){
      v0 = fmaf(wm[j].x, lo16(data[j]), v0);
      v1 = fmaf(wm[j].y, hi16(data[j]), v1);
    }
    if (lane >= 48){ v0 = 0.f; v1 = 0.f; }
    float mean, rstd;
    ln_butterfly(v0, v1, mean, rstd);
    const float y0 = (v0 - mean)*rstd*gg0 + be0;
    const float y1 = (v1 - mean)*rstd*gg1 + be1;
    y0r[tk] = y0; y1r[tk] = y1;

    if (sec == 0){
      const int token = bh*N_ + n;
      if (lane < 48){
        ((u32*)qp)  [(size_t)token*48 + lane] = pack2(y0, y1);
        ((u32*)Qaug)[(size_t)token*80 + lane] = pack2(y0*QSCALE_LOG2E, y1*QSCALE_LOG2E);
      }
    } else if (sec == 1){
      const int tl = n >> 4, nr = n & 15;
      if (lane < 48){
        const size_t idx = ((((size_t)bh*98 + tl)*5 + (lane>>4))*64
                           + ((lane&15)>>2)*16 + nr)*4 + (lane&3);
        ((u32*)Kt)[idx] = pack2(y0, y1);
      } else {
        const int m = lane - 48;
        u32 pr_[2];
        #pragma unroll
        for (int h2 = 0; h2 < 2; ++h2){
          u32 w_ = 0;
          #pragma unroll
          for (int e = 0; e < 2; ++e){
            const int jj = 4*m + 2*h2 + e;
            bool on = (jj < 14) ? (jj == hh) : (jj < 28) ? (jj-14 == ww)
                     : (jj < 36) ? (jj-28 == tt) : false;
            if (on) w_ |= (0x3F80u << (16*e));
          }
          pr_[h2] = w_;
        }
        const size_t bidx = ((((size_t)bh*98 + tl)*5 + (3 + (m>>3)))*64
                            + ((m&7)>>1)*16 + nr)*4 + 2*(m&1);
        *(uint2*)((u32*)Kt + bidx) = make_uint2(pr_[0], pr_[1]);
      }
    }
  }

  __syncthreads();   // all slab reads done -> slab reusable as scratch

  if (sec == 0){
    float* qtmp = (float*)&slab[0][0];      // [16][96] fp32
    #pragma unroll
    for (int tk = 0; tk < 2; ++tk){
      if (lane < 48){
        qtmp[((wid*2 + tk)*HD_) + c0]     = y0r[tk];
        qtmp[((wid*2 + tk)*HD_) + c0 + 1] = y1r[tk];
      }
    }
    __syncthreads();
    #pragma unroll 1
    for (int tk = 0; tk < 2; ++tk){
      const int u = wid*2 + tk;
      const int n = tok0 + u;
      const int token = bh*N_ + n;
      const int tt = n / HW_; const int rm = n % HW_;
      const int hh = rm / W_, ww = rm % W_;
      const float* qv = qtmp + u*HD_;
      if (lane < 36){
        const float* tb; int idx;
        if (lane < 14)      { tb = rph; idx = hh - lane      + 13; }
        else if (lane < 28) { tb = rpw; idx = ww - (lane-14) + 13; }
        else                { tb = rpt; idx = tt - (lane-28) +  7; }
        const float4* t4 = (const float4*)(tb + (size_t)idx*HD_);
        float acc = 0.f;
        #pragma unroll
        for (int i = 0; i < 24; ++i){
          const float4 rv = t4[i];
          acc += qv[4*i]*rv.x + qv[4*i+1]*rv.y + qv[4*i+2]*rv.z + qv[4*i+3]*rv.w;
        }
        Qaug[(size_t)token*CAUG_ + HD_ + lane] = f2b(acc * LOG2E);
      } else if (lane < 64){
        Qaug[(size_t)token*CAUG_ + HD_ + lane] = 0;
      }
    }
  } else if (sec == 2){
    u32* vres = (u32*)&slab[0][0];          // [16][48]
    #pragma unroll
    for (int tk = 0; tk < 2; ++tk){
      if (lane < 48) vres[(wid*2 + tk)*48 + lane] = pack2(y0r[tk], y1r[tk]);
    }
    __syncthreads();
    if (threadIdx.x < 2*HD_){
      const int grp = threadIdx.x / HD_, c = threadIdx.x % HD_;
      const int t0g = grp*8;
      u32 o[4];
      #pragma unroll
      for (int i = 0; i < 4; ++i){
        const u32 a = vres[(t0g + 2*i)*48 + (c>>1)], b = vres[(t0g + 2*i+1)*48 + (c>>1)];
        const u32 ra = (c&1) ? (a >> 16) : (a & 0xffffu);
        const u32 rb = (c&1) ? (b >> 16) : (b & 0xffffu);
        o[i] = ra | (rb << 16);
      }
      const int n0g = tok0 + t0g;
      const int pr = n0g >> 5, qd = (n0g & 31) >> 3;
      bf_t* dst = Vtt + ((((size_t)bh*49 + pr)*6 + (c>>4))*64 + qd*16 + (c&15))*8;
      *(uint4*)dst = make_uint4(o[0], o[1], o[2], o[3]);
    }
  }
}

// ---------------------------------------------------------------------------
// K4: MFMA flash attention, 8-wave in-block split-K, fragment-tiled K/V.
// ---------------------------------------------------------------------------
__global__ __launch_bounds__(512) void k_attn(
    const bf_t* __restrict__ Qaug, const bf_t* __restrict__ Kt,
    const bf_t* __restrict__ Vtt, const bf_t* __restrict__ qp,
    bf_t* __restrict__ attb){
  __shared__ __align__(16) short Pb[8][16][40];   // per-wave P tile (+8 pad)
  __shared__ float Os[8][16][96];                 // per-wave partial O
  __shared__ float ms[8][16], ls[8][16];          // per-wave partial m, l
  const int wid = threadIdx.x >> 6, lane = threadIdx.x & 63;
  const int bh = blockIdx.x / 98, qt = blockIdx.x % 98;
  const int q0 = qt*16;
  const int nl = lane & 15, quad = lane >> 4;

  bf16x8 qa[5];
  {
    const bf_t* Qrow = Qaug + ((size_t)bh*N_ + q0 + nl)*CAUG_ + quad*8;
    #pragma unroll
    for (int i = 0; i < 5; ++i) qa[i] = *(const bf16x8*)(Qrow + i*32);
  }
  short* Pw = &Pb[wid][0][0];

  f32x4 O[6];
  #pragma unroll
  for (int i = 0; i < 6; ++i) O[i] = (f32x4){0.f,0.f,0.f,0.f};
  float mc[4]   = {0.f,0.f,0.f,0.f};
  float rmax[4] = {-3e38f,-3e38f,-3e38f,-3e38f};
  float l[4]    = {0.f,0.f,0.f,0.f};

  auto s_tile = [&](int tl, int half){
    const bf_t* Kp = Kt + (((size_t)bh*98 + tl)*5*64 + lane)*8;
    f32x4 s = (f32x4){0.f,0.f,0.f,0.f};
    #pragma unroll
    for (int i = 0; i < 5; ++i)
      s = __builtin_amdgcn_mfma_f32_16x16x32_bf16(qa[i], *(const bf16x8*)(Kp + i*512), s, 0, 0, 0);
    #pragma unroll
    for (int r = 0; r < 4; ++r){
      rmax[r] = fmaxf(rmax[r], s[r]);
      const float p = exp2f(s[r] - mc[r]);
      l[r] += p;
      Pw[(quad*4 + r)*40 + half*16 + nl] = (short)f2b(p);
    }
  };
  auto rescale = [&](){
    #pragma unroll
    for (int r = 0; r < 4; ++r){
      float tm = rmax[r];
      tm = fmaxf(tm, __shfl_xor(tm, 1));
      tm = fmaxf(tm, __shfl_xor(tm, 2));
      tm = fmaxf(tm, __shfl_xor(tm, 4));
      tm = fmaxf(tm, __shfl_xor(tm, 8));
      const float mn = fmaxf(mc[r], tm);
      const float al = exp2f(mc[r] - mn);
      mc[r] = mn; l[r] *= al;
      #pragma unroll
      for (int ct = 0; ct < 6; ++ct) O[ct][r] *= al;
    }
  };

  const int p0 = (wid == 0) ? 0 : (7 + 6*(wid-1));
  const int npairs = (wid == 0) ? 7 : 6;
  #pragma unroll 1
  for (int pi = 0; pi < npairs; ++pi){
    const int kp = p0 + pi;
    s_tile(2*kp,     0);
    s_tile(2*kp + 1, 1);
    const bf16x8 pa = *(const bf16x8*)(Pw + nl*40 + quad*8);
    const bf_t* Vp = Vtt + (((size_t)bh*49 + kp)*6*64 + lane)*8;
    #pragma unroll
    for (int ct = 0; ct < 6; ++ct)
      O[ct] = __builtin_amdgcn_mfma_f32_16x16x32_bf16(pa, *(const bf16x8*)(Vp + ct*512), O[ct], 0, 0, 0);
    if (pi == npairs-1) rescale();
  }

  #pragma unroll
  for (int r = 0; r < 4; ++r){
    float ls_ = l[r];
    ls_ += __shfl_xor(ls_, 1); ls_ += __shfl_xor(ls_, 2);
    ls_ += __shfl_xor(ls_, 4); ls_ += __shfl_xor(ls_, 8);
    if (nl == 0){ ms[wid][quad*4 + r] = mc[r]; ls[wid][quad*4 + r] = ls_; }
    #pragma unroll
    for (int ct = 0; ct < 6; ++ct) Os[wid][quad*4 + r][ct*16 + nl] = O[ct][r];
  }
  __syncthreads();

  const int bb = bh >> 2, head = bh & 3;
  const int grow0 = bb*N_ + q0;                   // multiple of 16
  for (int e = threadIdx.x; e < 16*96; e += 512){
    const int row = e / 96, col = e % 96;
    float mx = -3e38f;
    #pragma unroll
    for (int w = 0; w < 8; ++w) mx = fmaxf(mx, ms[w][row]);
    float L = 0.f, A = 0.f;
    #pragma unroll
    for (int w = 0; w < 8; ++w){
      const float wt = exp2f(ms[w][row] - mx);
      L += wt*ls[w][row];
      A += wt*Os[w][row][col];
    }
    const float val = A/L + b2f(qp[((size_t)bh*N_ + q0 + row)*HD_ + col]);
    attb[ftidx(grow0 + row, head*HD_ + col)] = f2b(val);
  }
}

// ---------------------------------------------------------------------------
// K5: output projection via MFMA, fragment-tiled A/B, in-block split-K:
// 8 waves = 4 M-slots x 2 K-halves; kh=1 parks partials in LDS, kh=0 combines.
// Grid (49,6) = 294 blocks x 8 waves = 2352 waves.
// ---------------------------------------------------------------------------
__global__ __launch_bounds__(512) void k_proj(const bf_t* __restrict__ At,
    const bf_t* __restrict__ Wpt, const float* __restrict__ pb,
    float* __restrict__ out){
  __shared__ float part[4][16][64];               // 16 KB
  const int wid = threadIdx.x >> 6, lane = threadIdx.x & 63;
  const int ms = wid & 3, kh = wid >> 2;
  const int nl = lane & 15, quad = lane >> 4;
  const int mt  = blockIdx.x*4 + ms;
  const int nt0 = blockIdx.y*4;
  f32x4 acc[4];
  #pragma unroll
  for (int j = 0; j < 4; ++j) acc[j] = (f32x4){0.f,0.f,0.f,0.f};
  const bf_t* A0 = At  + ((size_t)mt*12*64 + lane)*8;
  const bf_t* B0 = Wpt + ((size_t)nt0*12*64 + lane)*8;
  #pragma unroll
  for (int ki = 0; ki < 6; ++ki){
    const int k0 = kh*6 + ki;
    const bf16x8 a0 = *(const bf16x8*)(A0 + k0*512);
    bf16x8 bf[4];
    #pragma unroll
    for (int j = 0; j < 4; ++j) bf[j] = *(const bf16x8*)(B0 + (size_t)(j*12 + k0)*512);
    #pragma unroll
    for (int j = 0; j < 4; ++j)
      acc[j] = __builtin_amdgcn_mfma_f32_16x16x32_bf16(a0, bf[j], acc[j], 0, 0, 0);
  }
  if (kh == 1){
    #pragma unroll
    for (int r = 0; r < 4; ++r)
      #pragma unroll
      for (int j = 0; j < 4; ++j)
        part[ms][quad*4 + r][j*16 + nl] = acc[j][r];
  }
  __syncthreads();
  if (kh == 0){
    #pragma unroll
    for (int r = 0; r < 4; ++r){
      const int m = mt*16 + quad*4 + r;
      #pragma unroll
      for (int j = 0; j < 4; ++j){
        const int col = (nt0 + j)*16 + nl;
        out[(size_t)m*DIM_ + col] = acc[j][r] + part[ms][quad*4 + r][j*16 + nl] + pb[col];
      }
    }
  }
}

// ---------------------------------------------------------------------------
extern "C" void kernel_launch(void* const* d_in, const int* in_sizes, int n_in,
                              void* d_out, int out_size, void* d_ws, size_t ws_size,
                              hipStream_t stream){
  const float* x      = (const float*)d_in[0];
  const float* qkv_w  = (const float*)d_in[1];
  const float* proj_w = (const float*)d_in[2];
  const float* proj_b = (const float*)d_in[3];
  const float* pqw    = (const float*)d_in[4];
  const float* pkw    = (const float*)d_in[5];
  const float* pvw    = (const float*)d_in[6];
  const float* nqw    = (const float*)d_in[7];
  const float* nqb    = (const float*)d_in[8];
  const float* nkw    = (const float*)d_in[9];
  const float* nkb    = (const float*)d_in[10];
  const float* nvw    = (const float*)d_in[11];
  const float* nvb    = (const float*)d_in[12];
  const float* rph    = (const float*)d_in[13];
  const float* rpw    = (const float*)d_in[14];
  const float* rpt    = (const float*)d_in[15];

  // Workspace (bytes), ~23.7 MB total. attb overlays raw_q after pooling.
  char* p = (char*)d_ws;
  const size_t RAW = (size_t)BH_*N_*HD_*2;       // 2,408,448 B
  const size_t AUG = (size_t)BH_*N_*CAUG_*2;     // 4,014,080 B
  bf_t* xb     = (bf_t*)(p);                     // frag-tiled
  bf_t* wqkvb  = (bf_t*)(p + RAW);               // frag-tiled
  bf_t* wprojb = (bf_t*)(p + RAW + 884736);      // frag-tiled
  char* p2 = p + RAW + 884736 + 294912;
  bf_t* raw_q  = (bf_t*)(p2);
  bf_t* raw_k  = (bf_t*)(p2 + RAW);
  bf_t* raw_v  = (bf_t*)(p2 + 2*RAW);
  bf_t* attb   = raw_q;                          // overlays raw_q (frag-tiled)
  bf_t* qp     = (bf_t*)(p2 + 3*RAW);
  bf_t* Qaug   = (bf_t*)(p2 + 4*RAW);
  bf_t* Kt     = (bf_t*)(p2 + 4*RAW + AUG);      // tiled Kaug
  bf_t* Vtt    = (bf_t*)(p2 + 4*RAW + 2*AUG);    // tiled V
  float* wtq   = (float*)(p2 + 4*RAW + 2*AUG + RAW);   // 3 x 27x96 fp32
  float* wtk   = wtq + 27*HD_;
  float* wtv   = wtk + 27*HD_;

  k_cast     <<<CAST_BLOCKS + 31, 256, 0, stream>>>(x, xb, qkv_w, wqkvb, proj_w, wprojb,
                                                    pqw, pkw, pvw, wtq, wtk, wtv);
  k_qkv      <<<dim3(49, 18),     256, 0, stream>>>(xb, wqkvb, raw_q, raw_k, raw_v);
  k_pool_slab<<<3*784,            512, 0, stream>>>(raw_q, raw_k, raw_v,
                                                    wtq, wtk, wtv,
                                                    nqw, nqb, nkw, nkb, nvw, nvb,
                                                    rph, rpw, rpt,
                                                    qp, Qaug, Kt, Vtt);
  k_attn     <<<BH_*98,           512, 0, stream>>>(Qaug, Kt, Vtt, qp, attb);
  k_proj     <<<dim3(49, 6),      512, 0, stream>>>(attb, wprojb, proj_b, (float*)d_out);
}

// Round 17
// 202.581 us; speedup vs baseline: 1.2010x; 1.2010x over previous
//
#include <hip/hip_runtime.h>

// Problem constants (fixed by reference)
#define B_    2
#define NH_   4
#define T_    8
#define H_    14
#define W_    14
#define HW_   196             // H*W
#define HD_   96
#define DIM_  384
#define N_    1568            // T*H*W
#define BH_   (B_*NH_)        // 8
#define BN_   (B_*N_)         // 3136
#define BHN_  (BH_*N_)        // 12544
#define CAUG_ 160             // 96 + 36 one-hot/bias + 28 pad

typedef unsigned short bf_t;
typedef unsigned int   u32;
typedef __attribute__((ext_vector_type(8))) short bf16x8;
typedef __attribute__((ext_vector_type(4))) float f32x4;

#define LOG2E 1.4426950408889634f
#define QSCALE_LOG2E 0.14724445f   /* 96^-0.5 * log2(e) */

static __device__ __forceinline__ float lo16(u32 v){ union{u32 i; float f;}x; x.i = v<<16;           return x.f; }
static __device__ __forceinline__ float hi16(u32 v){ union{u32 i; float f;}x; x.i = v & 0xffff0000u; return x.f; }
static __device__ __forceinline__ float b2f(bf_t v){ union{u32 i; float f;}x; x.i = ((u32)v)<<16;    return x.f; }
static __device__ __forceinline__ bf_t  f2b(float f){
  union{float f; u32 i;} x; x.f = f;
  return (bf_t)((x.i + 0x7fffu + ((x.i>>16)&1u)) >> 16);   // RNE
}
static __device__ __forceinline__ u32 pack2(float a, float b){
  return (u32)f2b(a) | ((u32)f2b(b) << 16);
}
// fragment-tile index for a row-major [R][384] matrix element (row, k)
static __device__ __forceinline__ size_t ftidx(int row, int k){
  return ((((size_t)(row>>4))*12 + (k>>5))*64 + ((k>>3)&3)*16 + (row&15))*8 + (k&7);
}

// ---------------------------------------------------------------------------
// K0: cast x / qkv_w / proj_w fp32 -> bf16 in FRAGMENT-TILED layout, plus
// conv-weight transpose [96][27]->[27][96] fp32 (last 31 blocks).
// ---------------------------------------------------------------------------
#define NA_ (BN_*DIM_)        // 1,204,224
#define NB_ (3*DIM_*DIM_)     //   442,368
#define NC_ (DIM_*DIM_)       //   147,456
#define CAST_BLOCKS ((NA_+NB_+NC_)/4/256)   // 1752 exactly

__global__ __launch_bounds__(256) void k_cast(
    const float* __restrict__ a, bf_t* __restrict__ ad,
    const float* __restrict__ b, bf_t* __restrict__ bd,
    const float* __restrict__ c, bf_t* __restrict__ cd,
    const float* __restrict__ wq, const float* __restrict__ wk,
    const float* __restrict__ wv, float* __restrict__ tq,
    float* __restrict__ tk, float* __restrict__ tv){
  if (blockIdx.x < CAST_BLOCKS){
    const int i = blockIdx.x*256 + threadIdx.x;     // float4 index
    const int i4 = i*4;
    float4 v; bf_t* dst; int row, k;
    if (i4 < NA_){
      v = ((const float4*)a)[i];
      dst = ad; row = i4/DIM_; k = i4%DIM_;
    } else if (i4 < NA_+NB_){
      const int f = i4 - NA_;
      v = ((const float4*)b)[i - NA_/4];
      dst = bd; row = f/DIM_; k = f%DIM_;
    } else {
      const int f = i4 - NA_ - NB_;
      v = ((const float4*)c)[i - (NA_+NB_)/4];
      dst = cd; row = f/DIM_; k = f%DIM_;
    }
    ushort4 o; o.x = f2b(v.x); o.y = f2b(v.y); o.z = f2b(v.z); o.w = f2b(v.w);
    *(ushort4*)(dst + ftidx(row, k)) = o;           // k%4==0 -> 8B aligned
  } else {
    const int idx = (blockIdx.x - CAST_BLOCKS)*256 + threadIdx.x;
    if (idx >= 3*HD_*27) return;
    const int t = idx / (HD_*27), rem = idx % (HD_*27);
    const int ch = rem / 27, j = rem % 27;
    const float* s = (t==0)? wq : (t==1)? wk : wv;
    float* d       = (t==0)? tq : (t==1)? tk : tv;
    d[j*HD_ + ch] = s[ch*27 + j];
  }
}

// ---------------------------------------------------------------------------
// K1: QKV GEMM via MFMA, fragment-tiled operands.
// ---------------------------------------------------------------------------
__global__ __launch_bounds__(256) void k_qkv(const bf_t* __restrict__ Xt,
    const bf_t* __restrict__ Wt,
    bf_t* __restrict__ q, bf_t* __restrict__ k, bf_t* __restrict__ v){
  const int wid = threadIdx.x >> 6, lane = threadIdx.x & 63;
  const int wr = wid & 1, wc = wid >> 1;
  const int nl = lane & 15, quad = lane >> 4;
  const int r0 = blockIdx.x*64 + wr*32;
  const int mt0 = r0 >> 4;
  const int nt0 = blockIdx.y*8 + wc*4;
  f32x4 acc[2][4];
  #pragma unroll
  for (int i = 0; i < 2; ++i)
    #pragma unroll
    for (int j = 0; j < 4; ++j) acc[i][j] = (f32x4){0.f,0.f,0.f,0.f};
  const bf_t* A0 = Xt + ((size_t)mt0*12*64 + lane)*8;
  const bf_t* B0 = Wt + ((size_t)nt0*12*64 + lane)*8;
  #pragma unroll 2
  for (int k0 = 0; k0 < 12; ++k0){
    const bf16x8 a0 = *(const bf16x8*)(A0 + k0*512);
    const bf16x8 a1 = *(const bf16x8*)(A0 + 12*512 + k0*512);
    bf16x8 bf[4];
    #pragma unroll
    for (int j = 0; j < 4; ++j) bf[j] = *(const bf16x8*)(B0 + (size_t)(j*12 + k0)*512);
    #pragma unroll
    for (int j = 0; j < 4; ++j){
      acc[0][j] = __builtin_amdgcn_mfma_f32_16x16x32_bf16(a0, bf[j], acc[0][j], 0, 0, 0);
      acc[1][j] = __builtin_amdgcn_mfma_f32_16x16x32_bf16(a1, bf[j], acc[1][j], 0, 0, 0);
    }
  }
  #pragma unroll
  for (int i = 0; i < 2; ++i){
    #pragma unroll
    for (int r = 0; r < 4; ++r){
      const int m  = r0 + i*16 + quad*4 + r;
      const int bb = m / N_, nn = m % N_;
      #pragma unroll
      for (int j = 0; j < 4; ++j){
        const int col = (nt0 + j)*16 + nl;
        const int s = col / DIM_, rem = col - s*DIM_;
        const int head = rem / HD_, hc = rem % HD_;
        bf_t* dst = (s==0) ? q : (s==1) ? k : v;
        dst[((size_t)(bb*NH_ + head)*N_ + nn)*HD_ + hc] = f2b(acc[i][j][r]);
      }
    }
  }
}

static __device__ __forceinline__ void ln_butterfly(
    float v0, float v1, float& mean, float& rstd){
  float s  = v0 + v1;
  float s2 = v0*v0 + v1*v1;
  #pragma unroll
  for (int off = 32; off > 0; off >>= 1){
    s  += __shfl_xor(s,  off);
    s2 += __shfl_xor(s2, off);
  }
  mean = s * (1.f/HD_);
  const float var = fmaxf(s2*(1.f/HD_) - mean*mean, 0.f);
  rstd = rsqrtf(var + 1e-6f);
}

// ---------------------------------------------------------------------------
// K2: LDS-slab pooled conv+LN, 16 tokens/block (4 waves x 4 tokens).
// Halo slab 162 rows (3t x 3h x 18w) x 96ch bf16 = 31.1 KB, coalesced stage.
// Flat grid 3*784: sec 0 = q (+rel), 1 = k -> Kt, 2 = v -> Vtt.  [R13 form]
// ---------------------------------------------------------------------------
__global__ __launch_bounds__(256) void k_pool_slab(
    const bf_t* __restrict__ qr_, const bf_t* __restrict__ kr_, const bf_t* __restrict__ vr_,
    const float* __restrict__ wtq, const float* __restrict__ wtk, const float* __restrict__ wtv,
    const float* __restrict__ gq, const float* __restrict__ bq,
    const float* __restrict__ gk, const float* __restrict__ bk,
    const float* __restrict__ gv, const float* __restrict__ bv,
    const float* __restrict__ rph, const float* __restrict__ rpw,
    const float* __restrict__ rpt,
    bf_t* __restrict__ qp, bf_t* __restrict__ Qaug,
    bf_t* __restrict__ Kt, bf_t* __restrict__ Vtt){
  __shared__ __align__(16) bf_t slab[162][HD_];   // 31,104 B
  __shared__ float qtmp[4][4][HD_];               //  6,144 B (q-section rel)
  __shared__ u32 vres[16][48];                    //  3,072 B (v-section repack)
  const int wid = threadIdx.x >> 6, lane = threadIdx.x & 63;
  const int sec = blockIdx.x / 784;
  const int rr_ = blockIdx.x % 784;
  const int bh = rr_ / 98, tok0 = (rr_ % 98)*16;
  const bf_t*  src = (sec==0)? qr_ : (sec==1)? kr_ : vr_;
  const float* wt  = (sec==0)? wtq : (sec==1)? wtk : wtv;
  const float* g   = (sec==0)? gq  : (sec==1)? gk  : gv;
  const float* be  = (sec==0)? bq  : (sec==1)? bk  : bv;
  const bf_t* base = src + (size_t)bh*N_*HD_;

  for (int li = threadIdx.x; li < 162*12; li += 256){
    const int rw = li / 12, ss = li % 12;
    const int aa = rw/54, bb2 = (rw%54)/18, cc = rw%18;
    int nn = tok0 + (aa-1)*HW_ + (bb2-1)*W_ + (cc-1);
    nn = min(max(nn, 0), N_-1);
    *(uint4*)&slab[rw][ss*8] = *(const uint4*)(base + (size_t)nn*HD_ + ss*8);
  }
  __syncthreads();

  const int c0 = (lane < 48) ? 2*lane : 0;
  float2 wgt[27];
  #pragma unroll
  for (int j = 0; j < 27; ++j) wgt[j] = *(const float2*)(wt + j*HD_ + c0);
  const float gg0 = g[c0], gg1 = g[c0+1], be0 = be[c0], be1 = be[c0+1];

  #pragma unroll 1
  for (int tk = 0; tk < 4; ++tk){
    const int u = wid*4 + tk;
    const int n = tok0 + u;
    const int tt = n / HW_; const int rm = n % HW_;
    const int hh = rm / W_, ww = rm % W_;
    float v0 = 0.f, v1 = 0.f;
    #pragma unroll
    for (int j = 0; j < 27; ++j){
      const int dt = j/9 - 1, dh = (j%9)/3 - 1, dw = j%3 - 1;
      const bool ok = ((unsigned)(tt+dt) < (unsigned)T_)
                   && ((unsigned)(hh+dh) < (unsigned)H_)
                   && ((unsigned)(ww+dw) < (unsigned)W_);
      const int rj = (dt+1)*54 + (dh+1)*18 + (dw + u + 1);
      u32 d = *(const u32*)&slab[rj][c0];
      d = ok ? d : 0u;
      v0 = fmaf(wgt[j].x, lo16(d), v0);
      v1 = fmaf(wgt[j].y, hi16(d), v1);
    }
    if (lane >= 48){ v0 = 0.f; v1 = 0.f; }
    float mean, rstd;
    ln_butterfly(v0, v1, mean, rstd);
    const float y0 = (v0 - mean)*rstd*gg0 + be0;
    const float y1 = (v1 - mean)*rstd*gg1 + be1;

    if (sec == 0){
      const int token = bh*N_ + n;
      if (lane < 48){
        ((u32*)qp)  [(size_t)token*48 + lane] = pack2(y0, y1);
        ((u32*)Qaug)[(size_t)token*80 + lane] = pack2(y0*QSCALE_LOG2E, y1*QSCALE_LOG2E);
        qtmp[wid][tk][c0] = y0; qtmp[wid][tk][c0+1] = y1;
      }
      __syncthreads();            // block-uniform branch (sec uniform)
      if (lane < 36){
        const float* tb; int idx;
        if (lane < 14)      { tb = rph; idx = hh - lane      + 13; }
        else if (lane < 28) { tb = rpw; idx = ww - (lane-14) + 13; }
        else                { tb = rpt; idx = tt - (lane-28) +  7; }
        const float4* t4 = (const float4*)(tb + (size_t)idx*HD_);
        float acc = 0.f;
        #pragma unroll
        for (int i = 0; i < 24; ++i){
          const float4 rv = t4[i];
          acc += qtmp[wid][tk][4*i]*rv.x + qtmp[wid][tk][4*i+1]*rv.y
               + qtmp[wid][tk][4*i+2]*rv.z + qtmp[wid][tk][4*i+3]*rv.w;
        }
        Qaug[(size_t)token*CAUG_ + HD_ + lane] = f2b(acc * LOG2E);
      } else if (lane < 64){
        Qaug[(size_t)token*CAUG_ + HD_ + lane] = 0;
      }
    } else if (sec == 1){
      const int tl = n >> 4, nr = n & 15;
      if (lane < 48){
        const size_t idx = ((((size_t)bh*98 + tl)*5 + (lane>>4))*64
                           + ((lane&15)>>2)*16 + nr)*4 + (lane&3);
        ((u32*)Kt)[idx] = pack2(y0, y1);
      } else {
        const int m = lane - 48;
        u32 pr_[2];
        #pragma unroll
        for (int h2 = 0; h2 < 2; ++h2){
          u32 w_ = 0;
          #pragma unroll
          for (int e = 0; e < 2; ++e){
            const int jj = 4*m + 2*h2 + e;
            bool on = (jj < 14) ? (jj == hh) : (jj < 28) ? (jj-14 == ww)
                     : (jj < 36) ? (jj-28 == tt) : false;
            if (on) w_ |= (0x3F80u << (16*e));
          }
          pr_[h2] = w_;
        }
        const size_t bidx = ((((size_t)bh*98 + tl)*5 + (3 + (m>>3)))*64
                            + ((m&7)>>1)*16 + nr)*4 + 2*(m&1);
        *(uint2*)((u32*)Kt + bidx) = make_uint2(pr_[0], pr_[1]);
      }
    } else {
      if (lane < 48) vres[u][lane] = pack2(y0, y1);
    }
  }

  if (sec == 2){
    __syncthreads();
    if (threadIdx.x < 2*HD_){
      const int grp = threadIdx.x / HD_, c = threadIdx.x % HD_;
      const int t0g = grp*8;
      u32 o[4];
      #pragma unroll
      for (int i = 0; i < 4; ++i){
        const u32 a = vres[t0g + 2*i][c>>1], b = vres[t0g + 2*i+1][c>>1];
        const u32 ra = (c&1) ? (a >> 16) : (a & 0xffffu);
        const u32 rb = (c&1) ? (b >> 16) : (b & 0xffffu);
        o[i] = ra | (rb << 16);
      }
      const int n0g = tok0 + t0g;
      const int pr = n0g >> 5, qd = (n0g & 31) >> 3;
      bf_t* dst = Vtt + ((((size_t)bh*49 + pr)*6 + (c>>4))*64 + qd*16 + (c&15))*8;
      *(uint4*)dst = make_uint4(o[0], o[1], o[2], o[3]);
    }
  }
}

// ---------------------------------------------------------------------------
// K4: MFMA flash attention, 8-wave in-block split-K, fragment-tiled K/V.
// Os partials stored BF16 (LDS 60.4 -> 35.8 KB => 4 blocks/CU, 2x waves).
// ---------------------------------------------------------------------------
__global__ __launch_bounds__(512) void k_attn(
    const bf_t* __restrict__ Qaug, const bf_t* __restrict__ Kt,
    const bf_t* __restrict__ Vtt, const bf_t* __restrict__ qp,
    bf_t* __restrict__ attb){
  __shared__ __align__(16) short Pb[8][16][40];   // per-wave P tile (+8 pad)
  __shared__ bf_t Os[8][16][96];                  // per-wave partial O (bf16)
  __shared__ float ms[8][16], ls[8][16];          // per-wave partial m, l
  const int wid = threadIdx.x >> 6, lane = threadIdx.x & 63;
  const int bh = blockIdx.x / 98, qt = blockIdx.x % 98;
  const int q0 = qt*16;
  const int nl = lane & 15, quad = lane >> 4;

  bf16x8 qa[5];
  {
    const bf_t* Qrow = Qaug + ((size_t)bh*N_ + q0 + nl)*CAUG_ + quad*8;
    #pragma unroll
    for (int i = 0; i < 5; ++i) qa[i] = *(const bf16x8*)(Qrow + i*32);
  }
  short* Pw = &Pb[wid][0][0];

  f32x4 O[6];
  #pragma unroll
  for (int i = 0; i < 6; ++i) O[i] = (f32x4){0.f,0.f,0.f,0.f};
  float mc[4]   = {0.f,0.f,0.f,0.f};
  float rmax[4] = {-3e38f,-3e38f,-3e38f,-3e38f};
  float l[4]    = {0.f,0.f,0.f,0.f};

  auto s_tile = [&](int tl, int half){
    const bf_t* Kp = Kt + (((size_t)bh*98 + tl)*5*64 + lane)*8;
    f32x4 s = (f32x4){0.f,0.f,0.f,0.f};
    #pragma unroll
    for (int i = 0; i < 5; ++i)
      s = __builtin_amdgcn_mfma_f32_16x16x32_bf16(qa[i], *(const bf16x8*)(Kp + i*512), s, 0, 0, 0);
    #pragma unroll
    for (int r = 0; r < 4; ++r){
      rmax[r] = fmaxf(rmax[r], s[r]);
      const float p = exp2f(s[r] - mc[r]);
      l[r] += p;
      Pw[(quad*4 + r)*40 + half*16 + nl] = (short)f2b(p);
    }
  };
  auto rescale = [&](){
    #pragma unroll
    for (int r = 0; r < 4; ++r){
      float tm = rmax[r];
      tm = fmaxf(tm, __shfl_xor(tm, 1));
      tm = fmaxf(tm, __shfl_xor(tm, 2));
      tm = fmaxf(tm, __shfl_xor(tm, 4));
      tm = fmaxf(tm, __shfl_xor(tm, 8));
      const float mn = fmaxf(mc[r], tm);
      const float al = exp2f(mc[r] - mn);
      mc[r] = mn; l[r] *= al;
      #pragma unroll
      for (int ct = 0; ct < 6; ++ct) O[ct][r] *= al;
    }
  };

  const int p0 = (wid == 0) ? 0 : (7 + 6*(wid-1));
  const int npairs = (wid == 0) ? 7 : 6;
  #pragma unroll 1
  for (int pi = 0; pi < npairs; ++pi){
    const int kp = p0 + pi;
    s_tile(2*kp,     0);
    s_tile(2*kp + 1, 1);
    const bf16x8 pa = *(const bf16x8*)(Pw + nl*40 + quad*8);
    const bf_t* Vp = Vtt + (((size_t)bh*49 + kp)*6*64 + lane)*8;
    #pragma unroll
    for (int ct = 0; ct < 6; ++ct)
      O[ct] = __builtin_amdgcn_mfma_f32_16x16x32_bf16(pa, *(const bf16x8*)(Vp + ct*512), O[ct], 0, 0, 0);
    if (pi == npairs-1) rescale();
  }

  #pragma unroll
  for (int r = 0; r < 4; ++r){
    float ls_ = l[r];
    ls_ += __shfl_xor(ls_, 1); ls_ += __shfl_xor(ls_, 2);
    ls_ += __shfl_xor(ls_, 4); ls_ += __shfl_xor(ls_, 8);
    if (nl == 0){ ms[wid][quad*4 + r] = mc[r]; ls[wid][quad*4 + r] = ls_; }
    #pragma unroll
    for (int ct = 0; ct < 6; ++ct) Os[wid][quad*4 + r][ct*16 + nl] = f2b(O[ct][r]);
  }
  __syncthreads();

  const int bb = bh >> 2, head = bh & 3;
  const int grow0 = bb*N_ + q0;                   // multiple of 16
  for (int e = threadIdx.x; e < 16*96; e += 512){
    const int row = e / 96, col = e % 96;
    float mx = -3e38f;
    #pragma unroll
    for (int w = 0; w < 8; ++w) mx = fmaxf(mx, ms[w][row]);
    float L = 0.f, A = 0.f;
    #pragma unroll
    for (int w = 0; w < 8; ++w){
      const float wt = exp2f(ms[w][row] - mx);
      L += wt*ls[w][row];
      A += wt*b2f(Os[w][row][col]);
    }
    const float val = A/L + b2f(qp[((size_t)bh*N_ + q0 + row)*HD_ + col]);
    attb[ftidx(grow0 + row, head*HD_ + col)] = f2b(val);
  }
}

// ---------------------------------------------------------------------------
// K5: output projection via MFMA, fragment-tiled A (attb) and B (Wpt).
// ---------------------------------------------------------------------------
__global__ __launch_bounds__(256) void k_proj(const bf_t* __restrict__ At,
    const bf_t* __restrict__ Wpt, const float* __restrict__ pb,
    float* __restrict__ out){
  const int wid = threadIdx.x >> 6, lane = threadIdx.x & 63;
  const int wr = wid & 1, wc = wid >> 1;
  const int nl = lane & 15, quad = lane >> 4;
  const int r0 = blockIdx.x*64 + wr*32;
  const int mt0 = r0 >> 4;
  const int nt0 = blockIdx.y*8 + wc*4;
  f32x4 acc[2][4];
  #pragma unroll
  for (int i = 0; i < 2; ++i)
    #pragma unroll
    for (int j = 0; j < 4; ++j) acc[i][j] = (f32x4){0.f,0.f,0.f,0.f};
  const bf_t* A0 = At  + ((size_t)mt0*12*64 + lane)*8;
  const bf_t* B0 = Wpt + ((size_t)nt0*12*64 + lane)*8;
  #pragma unroll 2
  for (int k0 = 0; k0 < 12; ++k0){
    const bf16x8 a0 = *(const bf16x8*)(A0 + k0*512);
    const bf16x8 a1 = *(const bf16x8*)(A0 + 12*512 + k0*512);
    bf16x8 bf[4];
    #pragma unroll
    for (int j = 0; j < 4; ++j) bf[j] = *(const bf16x8*)(B0 + (size_t)(j*12 + k0)*512);
    #pragma unroll
    for (int j = 0; j < 4; ++j){
      acc[0][j] = __builtin_amdgcn_mfma_f32_16x16x32_bf16(a0, bf[j], acc[0][j], 0, 0, 0);
      acc[1][j] = __builtin_amdgcn_mfma_f32_16x16x32_bf16(a1, bf[j], acc[1][j], 0, 0, 0);
    }
  }
  #pragma unroll
  for (int i = 0; i < 2; ++i){
    #pragma unroll
    for (int r = 0; r < 4; ++r){
      const int m = r0 + i*16 + quad*4 + r;
      #pragma unroll
      for (int j = 0; j < 4; ++j){
        const int col = (nt0 + j)*16 + nl;
        out[(size_t)m*DIM_ + col] = acc[i][j][r] + pb[col];
      }
    }
  }
}

// ---------------------------------------------------------------------------
extern "C" void kernel_launch(void* const* d_in, const int* in_sizes, int n_in,
                              void* d_out, int out_size, void* d_ws, size_t ws_size,
                              hipStream_t stream){
  const float* x      = (const float*)d_in[0];
  const float* qkv_w  = (const float*)d_in[1];
  const float* proj_w = (const float*)d_in[2];
  const float* proj_b = (const float*)d_in[3];
  const float* pqw    = (const float*)d_in[4];
  const float* pkw    = (const float*)d_in[5];
  const float* pvw    = (const float*)d_in[6];
  const float* nqw    = (const float*)d_in[7];
  const float* nqb    = (const float*)d_in[8];
  const float* nkw    = (const float*)d_in[9];
  const float* nkb    = (const float*)d_in[10];
  const float* nvw    = (const float*)d_in[11];
  const float* nvb    = (const float*)d_in[12];
  const float* rph    = (const float*)d_in[13];
  const float* rpw    = (const float*)d_in[14];
  const float* rpt    = (const float*)d_in[15];

  // Workspace (bytes), ~23.7 MB total. attb overlays raw_q after pooling.
  char* p = (char*)d_ws;
  const size_t RAW = (size_t)BH_*N_*HD_*2;       // 2,408,448 B
  const size_t AUG = (size_t)BH_*N_*CAUG_*2;     // 4,014,080 B
  bf_t* xb     = (bf_t*)(p);                     // frag-tiled
  bf_t* wqkvb  = (bf_t*)(p + RAW);               // frag-tiled
  bf_t* wprojb = (bf_t*)(p + RAW + 884736);      // frag-tiled
  char* p2 = p + RAW + 884736 + 294912;
  bf_t* raw_q  = (bf_t*)(p2);
  bf_t* raw_k  = (bf_t*)(p2 + RAW);
  bf_t* raw_v  = (bf_t*)(p2 + 2*RAW);
  bf_t* attb   = raw_q;                          // overlays raw_q (frag-tiled)
  bf_t* qp     = (bf_t*)(p2 + 3*RAW);
  bf_t* Qaug   = (bf_t*)(p2 + 4*RAW);
  bf_t* Kt     = (bf_t*)(p2 + 4*RAW + AUG);      // tiled Kaug
  bf_t* Vtt    = (bf_t*)(p2 + 4*RAW + 2*AUG);    // tiled V
  float* wtq   = (float*)(p2 + 4*RAW + 2*AUG + RAW);   // 3 x 27x96 fp32
  float* wtk   = wtq + 27*HD_;
  float* wtv   = wtk + 27*HD_;

  k_cast     <<<CAST_BLOCKS + 31, 256, 0, stream>>>(x, xb, qkv_w, wqkvb, proj_w, wprojb,
                                                    pqw, pkw, pvw, wtq, wtk, wtv);
  k_qkv      <<<dim3(BN_/64, 9),  256, 0, stream>>>(xb, wqkvb, raw_q, raw_k, raw_v);
  k_pool_slab<<<3*784,            256, 0, stream>>>(raw_q, raw_k, raw_v,
                                                    wtq, wtk, wtv,
                                                    nqw, nqb, nkw, nkb, nvw, nvb,
                                                    rph, rpw, rpt,
                                                    qp, Qaug, Kt, Vtt);
  k_attn     <<<BH_*98,           512, 0, stream>>>(Qaug, Kt, Vtt, qp, attb);
  k_proj     <<<dim3(BN_/64, 3),  256, 0, stream>>>(attb, wprojb, proj_b, (float*)d_out);
}